// Round 7
// baseline (1623.970 us; speedup 1.0000x reference)
//
#include <hip/hip_runtime.h>
#include <hip/hip_cooperative_groups.h>

namespace cg = cooperative_groups;

typedef __attribute__((ext_vector_type(8))) short frag_ab;   // 8 bf16 = 4 VGPRs
typedef __attribute__((ext_vector_type(4))) float frag_cd;   // 4 fp32 acc

__device__ __forceinline__ short f2bf(float f) {
  union { float f; unsigned u; } v; v.f = f;
  unsigned r = v.u + 0x7fffu + ((v.u >> 16) & 1u);   // RNE
  return (short)(r >> 16);
}
__device__ __forceinline__ float bf2f(short s) {
  union { unsigned u; float f; } v; v.u = ((unsigned)(unsigned short)s) << 16;
  return v.f;
}

// ---------------------------------------------------------------------------
// wconv: fp32 weights [nmat][Keff][64] -> MFMA B-fragment-ordered bf16.
// ---------------------------------------------------------------------------
__device__ __forceinline__ void wconv_body(
    const float* __restrict__ W, short* __restrict__ out,
    int Keff, int S, int nmat, int tid)
{
  int per = S * 4 * 64;
  if (tid >= nmat * per) return;
  int m = tid / per, r = tid % per;
  int s = r / 256, ct = (r >> 6) & 3, ln = r & 63;
  const float* Wm = W + (size_t)m * Keff * 64;
  __align__(16) short tmp[8];
  for (int j = 0; j < 8; ++j) {
    int k = s * 32 + (ln >> 4) * 8 + j;
    int n = ct * 16 + (ln & 15);
    tmp[j] = (k < Keff) ? f2bf(Wm[k * 64 + n]) : (short)0;
  }
  *(uint4*)&out[((size_t)m * per + (size_t)(s * 4 + ct) * 64 + ln) * 8] = *(uint4*)tmp;
}

__global__ void wconv_all(const float* __restrict__ pw,
                          const float* __restrict__ u2w,
                          const float* __restrict__ u1w,
                          short* projt, short* u2t, short* u1t)
{
  int b = blockIdx.x, t = threadIdx.x;
  if (b < 3)        wconv_body(pw,  projt, 75,  3, 1, b * 256 + t);
  else if (b < 12)  wconv_body(u2w, u2t,   80,  3, 3, (b - 3) * 256 + t);
  else              wconv_body(u1w, u1t,   128, 4, 3, (b - 12) * 256 + t);
}

// ---------------------------------------------------------------------------
// proj: hbf = bf16(x @ pw + pb).
// ---------------------------------------------------------------------------
#define AS1 104
__global__ __launch_bounds__(256, 4) void proj_kernel(
    const float* __restrict__ x, const short* __restrict__ wt,
    const float* __restrict__ bias, short* __restrict__ hbf, int N)
{
  __shared__ __align__(16) short A[128 * AS1];
  int t = threadIdx.x;
  int nb = blockIdx.x * 128;
  int ln = t & 63;
  frag_ab bf[12];
  for (int s = 0; s < 3; ++s)
    for (int ct = 0; ct < 4; ++ct)
      bf[s * 4 + ct] = *(const frag_ab*)&wt[((size_t)(s * 4 + ct) * 64 + ln) * 8];
  for (int i = 0; i < 48; ++i) {
    int q = i * 256 + t; int el = q / 96; int c = q - el * 96;
    int rg = nb + el;
    float v = (c < 75 && rg < N) ? x[rg * 75 + c] : 0.f;
    A[el * AS1 + c] = f2bf(v);
  }
  __syncthreads();
  int wv = t >> 6;
  int lrow = ln & 15, lk = ln >> 4;
  frag_cd acc[2][4];
  for (int rt = 0; rt < 2; ++rt) for (int ct = 0; ct < 4; ++ct) {
    frag_cd z = {0.f, 0.f, 0.f, 0.f}; acc[rt][ct] = z;
  }
  for (int s = 0; s < 3; ++s) {
    frag_ab a0 = *(const frag_ab*)&A[(wv*32 + lrow) * AS1 + s*32 + lk*8];
    frag_ab a1 = *(const frag_ab*)&A[(wv*32 + 16 + lrow) * AS1 + s*32 + lk*8];
    for (int ct = 0; ct < 4; ++ct) {
      acc[0][ct] = __builtin_amdgcn_mfma_f32_16x16x32_bf16(a0, bf[s*4+ct], acc[0][ct], 0, 0, 0);
      acc[1][ct] = __builtin_amdgcn_mfma_f32_16x16x32_bf16(a1, bf[s*4+ct], acc[1][ct], 0, 0, 0);
    }
  }
  float bv[4];
  for (int ct = 0; ct < 4; ++ct) bv[ct] = bias[ct*16 + lrow];
  for (int rt = 0; rt < 2; ++rt)
    for (int ct = 0; ct < 4; ++ct)
      for (int r = 0; r < 4; ++r) {
        int row = wv*32 + rt*16 + lk*4 + r;
        int rg = nb + row;
        if (rg < N) hbf[(size_t)rg * 64 + ct*16 + lrow] = f2bf(acc[rt][ct][r] + bv[ct]);
      }
}

// ---------------------------------------------------------------------------
// hist: counting-sort histogram + rank, and attr fp32->bf16 (edge order).
// ---------------------------------------------------------------------------
__global__ __launch_bounds__(256) void hist_kernel(
    const int* __restrict__ dst, const float* __restrict__ attr,
    int* __restrict__ counts, int* __restrict__ rank,
    uint4* __restrict__ abf, int E)
{
  int i = blockIdx.x * 256 + threadIdx.x;
  if (i < E) {
    rank[i] = atomicAdd(&counts[dst[i]], 1);
    const float4* a4 = (const float4*)(attr + (size_t)i * 16);
    float4 v0 = a4[0], v1 = a4[1], v2 = a4[2], v3 = a4[3];
    __align__(16) short tmp[16];
    tmp[0]=f2bf(v0.x); tmp[1]=f2bf(v0.y); tmp[2]=f2bf(v0.z); tmp[3]=f2bf(v0.w);
    tmp[4]=f2bf(v1.x); tmp[5]=f2bf(v1.y); tmp[6]=f2bf(v1.z); tmp[7]=f2bf(v1.w);
    tmp[8]=f2bf(v2.x); tmp[9]=f2bf(v2.y); tmp[10]=f2bf(v2.z); tmp[11]=f2bf(v2.w);
    tmp[12]=f2bf(v3.x); tmp[13]=f2bf(v3.y); tmp[14]=f2bf(v3.z); tmp[15]=f2bf(v3.w);
    uint4* rp = abf + (size_t)i * 2;
    rp[0] = *(uint4*)&tmp[0];
    rp[1] = *(uint4*)&tmp[8];
  }
}

#define SCAN_TILE 2048
__global__ __launch_bounds__(256) void scan_k1(
    const int* __restrict__ counts, int* __restrict__ offsets,
    int* __restrict__ bsum, int n)
{
  __shared__ int ts[256];
  int t = threadIdx.x;
  int base = blockIdx.x * SCAN_TILE + t * 8;
  int v[8]; int s = 0;
  for (int j = 0; j < 8; ++j) { v[j] = (base + j < n) ? counts[base + j] : 0; s += v[j]; }
  ts[t] = s; __syncthreads();
  for (int off = 1; off < 256; off <<= 1) {
    int x = (t >= off) ? ts[t - off] : 0;
    __syncthreads();
    ts[t] += x;
    __syncthreads();
  }
  if (t == 255) bsum[blockIdx.x] = ts[255];
  int run = (t > 0) ? ts[t - 1] : 0;
  for (int j = 0; j < 8; ++j) { if (base + j < n) offsets[base + j] = run; run += v[j]; }
}

__global__ __launch_bounds__(256) void scan_k3(
    int* __restrict__ offsets, const int* __restrict__ bsum, int n, int nb)
{
  __shared__ int adds;
  int t = threadIdx.x;
  if (t < 64) {
    int v = (t < nb) ? bsum[t] : 0;
    int x = v;
    for (int o = 1; o < 64; o <<= 1) { int y = __shfl_up(x, o); if (t >= o) x += y; }
    int b = blockIdx.x;
    int a = __shfl(x, b - 1);
    if (t == 0) adds = (b == 0) ? 0 : a;
  }
  __syncthreads();
  int add = adds;
  int base = blockIdx.x * SCAN_TILE + t;
  for (int j = 0; j < 8; ++j) { int i = base + j * 256; if (i < n) offsets[i] += add; }
}

// ---------------------------------------------------------------------------
// scatter: packed uint2 record {src(17)|dst[14:0]<<17, dst[16:15]|e<<2} per
// edge (8 B scattered). Tail: zero agg (scratch no longer overlays agg).
// ---------------------------------------------------------------------------
__global__ __launch_bounds__(256) void scatter_kernel(
    const int* __restrict__ src, const int* __restrict__ dst,
    const int* __restrict__ offsets, const int* __restrict__ rank,
    uint2* __restrict__ rec2, float* __restrict__ agg, int N, int E)
{
  int e = blockIdx.x * 256 + threadIdx.x;
  if (e < E) {
    int d = dst[e];
    int p = offsets[d] + rank[e];
    unsigned s = (unsigned)src[e];
    unsigned w0 = s | ((unsigned)(d & 0x7FFF) << 17);
    unsigned w1 = (unsigned)(d >> 15) | ((unsigned)e << 2);
    rec2[p] = make_uint2(w0, w1);
  }
  // zero agg (N*16 float4 elements), grid-stride
  float4 z4 = make_float4(0.f, 0.f, 0.f, 0.f);
  int tot = N * 16;
  int stride = gridDim.x * 256;
  for (int z = blockIdx.x * 256 + threadIdx.x; z < tot; z += stride)
    ((float4*)agg)[z] = z4;
}

// ---------------------------------------------------------------------------
// mega: persistent cooperative kernel for the 3-layer loop.
//   msg phase: each block owns a contiguous XCD-swizzled chunk of 128-edge
//   tiles, software-pipelined depth-2 (rec[i+2] in flight, gathers[i+1] in
//   flight, compute tile i) so gather latency hides under MFMA+reduce.
//   grid.sync() between phases replaces 5 kernel boundaries.
// Numerics bit-identical to the proven 114-us msg/upd pair.
// ---------------------------------------------------------------------------
#define MS 68

__device__ __forceinline__ void rec_load(
    int tile, int E, int lo, int lrow, const uint2* __restrict__ rec2,
    uint2& r0, uint2& r1)
{
  int g0 = (tile << 7) + lo + lrow;
  int g1 = g0 + 16;
  int p0 = g0 > E - 1 ? E - 1 : g0;
  int p1 = g1 > E - 1 ? E - 1 : g1;
  r0 = rec2[p0];
  r1 = rec2[p1];
}

__device__ __forceinline__ void gather_issue(
    int tile, int E, int lo, int lrow, int lk,
    uint2 r0, uint2 r1,
    const short* __restrict__ hbf, const uint4* __restrict__ abf,
    int& d0, int& d1,
    frag_ab& a00, frag_ab& a01, frag_ab& a10, frag_ab& a11,
    frag_ab& a20, frag_ab& a21)
{
  int g0 = (tile << 7) + lo + lrow;
  int g1 = g0 + 16;
  int s0 = (int)(r0.x & 0x1FFFFu);
  int s1 = (int)(r1.x & 0x1FFFFu);
  d0 = (g0 < E) ? (int)((r0.x >> 17) | ((r0.y & 3u) << 15)) : -1;
  d1 = (g1 < E) ? (int)((r1.x >> 17) | ((r1.y & 3u) << 15)) : -1;
  int e0 = (int)(r0.y >> 2);
  int e1 = (int)(r1.y >> 2);
  a00 = *(const frag_ab*)&hbf[(size_t)s0 * 64 + lk*8];
  a01 = *(const frag_ab*)&hbf[(size_t)s1 * 64 + lk*8];
  a10 = *(const frag_ab*)&hbf[(size_t)s0 * 64 + 32 + lk*8];
  a11 = *(const frag_ab*)&hbf[(size_t)s1 * 64 + 32 + lk*8];
  frag_ab z8 = {0,0,0,0,0,0,0,0};
  a20 = z8; a21 = z8;
  if (lk < 2) {
    a20 = *(const frag_ab*)((const short*)abf + (size_t)e0 * 16 + lk*8);
    a21 = *(const frag_ab*)((const short*)abf + (size_t)e1 * 16 + lk*8);
  }
}

__global__ __launch_bounds__(256, 5) void mega_kernel(
    short* __restrict__ hbf, const uint2* __restrict__ rec2,
    const uint4* __restrict__ abf,
    const short* __restrict__ u2t, const float* __restrict__ u2b,
    const short* __restrict__ u1t, const float* __restrict__ u1b,
    float* __restrict__ agg, float* __restrict__ hout,
    int N, int E)
{
  cg::grid_group grid = cg::this_grid();
  __shared__ short M2[128 * MS];                 // 17408 B
  const int t = threadIdx.x;
  const int ln = t & 63;
  const int wv = t >> 6;
  const int lrow = ln & 15, lk = ln >> 4;
  const int lo = wv * 32;
  const int EB = (E + 127) >> 7;
  const int NBT = (N + 63) >> 6;
  const int nwg = gridDim.x;
  // bijective XCD-aware remap for chunk assignment
  int qq = nwg >> 3, rr = nwg & 7;
  int xcd = blockIdx.x & 7, bi = blockIdx.x >> 3;
  int bsz = (xcd < rr ? xcd * (qq + 1) : rr * (qq + 1) + (xcd - rr) * qq) + bi;
  const int chunk = (EB + nwg - 1) / nwg;
  const int t0 = bsz * chunk;

  for (int l = 0; l < 3; ++l) {
    // ======================= msg phase =======================
    {
      const short* wt = u2t + (size_t)l * 6144;
      const float* bias = u2b + (size_t)l * 64;
      float bv[4] = { bias[lrow], bias[16 + lrow], bias[32 + lrow], bias[48 + lrow] };

      // pipeline prologue: tile t0 gathers, rec for t0+1
      uint2 ra0, ra1, rb0, rb1;
      int dc0, dc1;
      frag_ab c00, c01, c10, c11, c20, c21;
      rec_load(t0, E, lo, lrow, rec2, ra0, ra1);
      gather_issue(t0, E, lo, lrow, lk, ra0, ra1, hbf, abf,
                   dc0, dc1, c00, c01, c10, c11, c20, c21);
      rec_load(t0 + 1, E, lo, lrow, rec2, ra0, ra1);

      for (int i = 0; i < chunk; ++i) {
        // stage 1: rec for tile i+2 in flight
        rec_load(t0 + i + 2, E, lo, lrow, rec2, rb0, rb1);
        // stage 2: decode rec[i+1] (arrived), issue its gathers
        int dn0, dn1;
        frag_ab n00, n01, n10, n11, n20, n21;
        gather_issue(t0 + i + 1, E, lo, lrow, lk, ra0, ra1, hbf, abf,
                     dn0, dn1, n00, n01, n10, n11, n20, n21);

        // stage 3: compute tile i from current frags (two rt passes, acc[4])
#pragma unroll
        for (int rt = 0; rt < 2; ++rt) {
          frag_ab A0 = rt ? c01 : c00;
          frag_ab A1 = rt ? c11 : c10;
          frag_ab A2 = rt ? c21 : c20;
          frag_cd acc[4];
#pragma unroll
          for (int ct = 0; ct < 4; ++ct) {
            frag_cd z = {0.f, 0.f, 0.f, 0.f}; acc[ct] = z;
          }
#pragma unroll
          for (int s2 = 0; s2 < 3; ++s2) {
            frag_ab A = (s2 == 0) ? A0 : ((s2 == 1) ? A1 : A2);
#pragma unroll
            for (int ct = 0; ct < 4; ++ct) {
              frag_ab bb = *(const frag_ab*)&wt[((size_t)(s2 * 4 + ct) * 64 + ln) * 8];
              acc[ct] = __builtin_amdgcn_mfma_f32_16x16x32_bf16(A, bb, acc[ct], 0, 0, 0);
            }
          }
#pragma unroll
          for (int ct = 0; ct < 4; ++ct)
#pragma unroll
            for (int r = 0; r < 4; ++r) {
              int row = lo + rt * 16 + lk * 4 + r;
              float m = acc[ct][r] + bv[ct];
              m = m > 0.f ? m : 0.1f * m;        // LeakyReLU(0.1)
              M2[row * MS + ct * 16 + lrow] = f2bf(m);
            }
        }
        __asm__ __volatile__("s_waitcnt lgkmcnt(0)" ::: "memory");  // wave-local

        // run structure + segmented reduce + agg stores
        int dl = (ln < 16) ? dc0 : dc1;
        int dnext = __shfl_down(dl, 1);
        bool end = (ln < 32) && ((ln == 31) || (dl != dnext));
        unsigned em = (unsigned)__ballot(end);
        unsigned cm = em & ~(em & (0u - em)) & 0x7fffffffu;
        float s = 0.f;
#pragma unroll
        for (int i2 = 0; i2 < 32; ++i2) {
          s += bf2f(M2[(lo + i2) * MS + ln]);
          if ((em >> i2) & 1u) {
            int di = (i2 < 16) ? __shfl(dc0, i2) : __shfl(dc1, i2 - 16);
            if (di >= 0) {
              float* dest = &agg[(size_t)di * 64 + ln];
              if ((cm >> i2) & 1u) *dest = s;
              else unsafeAtomicAdd(dest, s);
            }
            s = 0.f;
          }
        }

        // rotate pipeline registers
        dc0 = dn0; dc1 = dn1;
        c00 = n00; c01 = n01; c10 = n10; c11 = n11; c20 = n20; c21 = n21;
        ra0 = rb0; ra1 = rb1;
      }
    }
    grid.sync();

    // ======================= upd phase =======================
    {
      const short* wt = u1t + (size_t)l * 8192;
      const float* bias = u1b + (size_t)l * 64;
      int last = (l == 2);
      float bv[4] = { bias[lrow], bias[16 + lrow], bias[32 + lrow], bias[48 + lrow] };
      for (int tt = blockIdx.x; tt < NBT; tt += nwg) {
        int nb = tt << 6;
        int rr0 = nb + wv * 16 + lrow;
        frag_ab z8 = {0,0,0,0,0,0,0,0};
        frag_ab a[4];
        a[0] = (rr0 < N) ? *(const frag_ab*)&hbf[(size_t)rr0 * 64 + lk*8]      : z8;
        a[1] = (rr0 < N) ? *(const frag_ab*)&hbf[(size_t)rr0 * 64 + 32 + lk*8] : z8;
#pragma unroll
        for (int si = 0; si < 2; ++si) {
          int cb = si * 32 + lk * 8;
          frag_ab af = z8;
          if (rr0 < N) {
            float* ap = &agg[(size_t)rr0 * 64 + cb];
            float4 v0 = *(const float4*)ap;
            float4 v1 = *(const float4*)(ap + 4);
            af[0]=f2bf(v0.x); af[1]=f2bf(v0.y); af[2]=f2bf(v0.z); af[3]=f2bf(v0.w);
            af[4]=f2bf(v1.x); af[5]=f2bf(v1.y); af[6]=f2bf(v1.z); af[7]=f2bf(v1.w);
            if (!last) {
              float4 z = make_float4(0.f, 0.f, 0.f, 0.f);
              *(float4*)ap = z; *(float4*)(ap + 4) = z;
            }
          }
          a[2 + si] = af;
        }
        frag_cd acc[4];
#pragma unroll
        for (int ct = 0; ct < 4; ++ct) {
          frag_cd z = {0.f, 0.f, 0.f, 0.f}; acc[ct] = z;
        }
#pragma unroll
        for (int s = 0; s < 4; ++s)
#pragma unroll
          for (int ct = 0; ct < 4; ++ct) {
            frag_ab b = *(const frag_ab*)&wt[((size_t)(s * 4 + ct) * 64 + ln) * 8];
            acc[ct] = __builtin_amdgcn_mfma_f32_16x16x32_bf16(a[s], b, acc[ct], 0, 0, 0);
          }
#pragma unroll
        for (int ct = 0; ct < 4; ++ct)
#pragma unroll
          for (int r = 0; r < 4; ++r) {
            int rg = nb + wv * 16 + lk * 4 + r;
            if (rg < N) {
              float v = acc[ct][r] + bv[ct];
              if (last) hout[(size_t)rg * 64 + ct * 16 + lrow] = v;
              hbf[(size_t)rg * 64 + ct * 16 + lrow] = f2bf(v);
            }
          }
      }
    }
    grid.sync();
  }
}

extern "C" void kernel_launch(void* const* d_in, const int* in_sizes, int n_in,
                              void* d_out, int out_size, void* d_ws, size_t ws_size,
                              hipStream_t stream) {
  const float* x    = (const float*)d_in[0];
  const int*   ei   = (const int*)d_in[1];
  const float* attr = (const float*)d_in[2];
  const float* pw   = (const float*)d_in[3];
  const float* pb   = (const float*)d_in[4];
  const float* u2w  = (const float*)d_in[5];
  const float* u2b  = (const float*)d_in[6];
  const float* u1w  = (const float*)d_in[7];
  const float* u1b  = (const float*)d_in[8];

  const int N = in_sizes[0] / 75;
  const int E = in_sizes[1] / 2;
  const int* src = ei;
  const int* dst = ei + E;

  float* hout = (float*)d_out;
  char*  ws   = (char*)d_ws;
  size_t nh   = (size_t)N * 64;
  size_t off  = 0;
  short* hbf   = (short*)(ws + off); off += nh * 2;              //  12.8 MB
  float* agg   = (float*)(ws + off); off += nh * 4;              //  25.6 MB
  uint2* rec2  = (uint2*)(ws + off); off += (size_t)E * 8;       //  12.8 MB
  uint4* abf_e = (uint4*)(ws + off); off += (size_t)E * 32;      //  51.2 MB
  int*   counts  = (int*)(ws + off); off += (size_t)N * 4;
  int*   offsets = (int*)(ws + off); off += (size_t)N * 4;
  int*   bsum    = (int*)(ws + off); off += 64 * 4;
  int*   rank    = (int*)(ws + off); off += (size_t)E * 4;
  short* projt = (short*)(ws + off); off += 3 * 4 * 64 * 8 * 2;
  short* u2t   = (short*)(ws + off); off += (size_t)3 * 3 * 4 * 64 * 8 * 2;
  short* u1t   = (short*)(ws + off); off += (size_t)3 * 4 * 4 * 64 * 8 * 2;

  const int NB = (N + 127) / 128;
  const int GE = (E + 255) / 256;
  const int NS = (N + SCAN_TILE - 1) / SCAN_TILE;

  // cooperative grid size (cached across calls)
  static int nblk = 0;
  if (nblk == 0) {
    int mb = 0;
    hipError_t err = hipOccupancyMaxActiveBlocksPerMultiprocessor(
        &mb, mega_kernel, 256, 0);
    int ncu = 256;
    hipDeviceProp_t prop;
    if (hipGetDeviceProperties(&prop, 0) == hipSuccess && prop.multiProcessorCount > 0)
      ncu = prop.multiProcessorCount;
    if (err != hipSuccess || mb < 1) mb = 4;
    if (mb > 5) mb = 5;
    nblk = mb * ncu;
  }

  // one-time preprocessing
  wconv_all<<<24, 256, 0, stream>>>(pw, u2w, u1w, projt, u2t, u1t);
  proj_kernel<<<NB, 256, 0, stream>>>(x, projt, pb, hbf, N);
  hipMemsetAsync(counts, 0, (size_t)N * 4, stream);
  hist_kernel<<<GE, 256, 0, stream>>>(dst, attr, counts, rank, abf_e, E);
  scan_k1<<<NS, 256, 0, stream>>>(counts, offsets, bsum, N);
  scan_k3<<<NS, 256, 0, stream>>>(offsets, bsum, N, NS);
  scatter_kernel<<<GE, 256, 0, stream>>>(src, dst, offsets, rank, rec2, agg, N, E);

  // 3-layer loop as one persistent cooperative kernel
  int Nv = N, Ev = E;
  void* kargs[] = {
    (void*)&hbf, (void*)&rec2, (void*)&abf_e,
    (void*)&u2t, (void*)&u2b, (void*)&u1t, (void*)&u1b,
    (void*)&agg, (void*)&hout, (void*)&Nv, (void*)&Ev
  };
  hipLaunchCooperativeKernel((void*)mega_kernel, dim3(nblk), dim3(256),
                             kargs, 0, stream);
}

// Round 8
// 748.350 us; speedup vs baseline: 2.1701x; 2.1701x over previous
//
#include <hip/hip_runtime.h>

typedef __attribute__((ext_vector_type(8))) short frag_ab;   // 8 bf16 = 4 VGPRs
typedef __attribute__((ext_vector_type(4))) float frag_cd;   // 4 fp32 acc

__device__ __forceinline__ short f2bf(float f) {
  union { float f; unsigned u; } v; v.f = f;
  unsigned r = v.u + 0x7fffu + ((v.u >> 16) & 1u);   // RNE
  return (short)(r >> 16);
}
__device__ __forceinline__ float bf2f(short s) {
  union { unsigned u; float f; } v; v.u = ((unsigned)(unsigned short)s) << 16;
  return v.f;
}

// ---------------------------------------------------------------------------
// wconv: fp32 weights [nmat][Keff][64] -> MFMA B-fragment-ordered bf16.
// ---------------------------------------------------------------------------
__device__ __forceinline__ void wconv_body(
    const float* __restrict__ W, short* __restrict__ out,
    int Keff, int S, int nmat, int tid)
{
  int per = S * 4 * 64;
  if (tid >= nmat * per) return;
  int m = tid / per, r = tid % per;
  int s = r / 256, ct = (r >> 6) & 3, ln = r & 63;
  const float* Wm = W + (size_t)m * Keff * 64;
  __align__(16) short tmp[8];
  for (int j = 0; j < 8; ++j) {
    int k = s * 32 + (ln >> 4) * 8 + j;
    int n = ct * 16 + (ln & 15);
    tmp[j] = (k < Keff) ? f2bf(Wm[k * 64 + n]) : (short)0;
  }
  *(uint4*)&out[((size_t)m * per + (size_t)(s * 4 + ct) * 64 + ln) * 8] = *(uint4*)tmp;
}

__global__ void wconv_all(const float* __restrict__ pw,
                          const float* __restrict__ u2w,
                          const float* __restrict__ u1w,
                          short* projt, short* u2t, short* u1t)
{
  int b = blockIdx.x, t = threadIdx.x;
  if (b < 3)        wconv_body(pw,  projt, 75,  3, 1, b * 256 + t);
  else if (b < 12)  wconv_body(u2w, u2t,   80,  3, 3, (b - 3) * 256 + t);
  else              wconv_body(u1w, u1t,   128, 4, 3, (b - 12) * 256 + t);
}

// ---------------------------------------------------------------------------
// proj: hbf = bf16(x @ pw + pb).
// ---------------------------------------------------------------------------
#define AS1 104
__global__ __launch_bounds__(256, 4) void proj_kernel(
    const float* __restrict__ x, const short* __restrict__ wt,
    const float* __restrict__ bias, short* __restrict__ hbf, int N)
{
  __shared__ __align__(16) short A[128 * AS1];
  int t = threadIdx.x;
  int nb = blockIdx.x * 128;
  int ln = t & 63;
  frag_ab bf[12];
  for (int s = 0; s < 3; ++s)
    for (int ct = 0; ct < 4; ++ct)
      bf[s * 4 + ct] = *(const frag_ab*)&wt[((size_t)(s * 4 + ct) * 64 + ln) * 8];
  for (int i = 0; i < 48; ++i) {
    int q = i * 256 + t; int el = q / 96; int c = q - el * 96;
    int rg = nb + el;
    float v = (c < 75 && rg < N) ? x[rg * 75 + c] : 0.f;
    A[el * AS1 + c] = f2bf(v);
  }
  __syncthreads();
  int wv = t >> 6;
  int lrow = ln & 15, lk = ln >> 4;
  frag_cd acc[2][4];
  for (int rt = 0; rt < 2; ++rt) for (int ct = 0; ct < 4; ++ct) {
    frag_cd z = {0.f, 0.f, 0.f, 0.f}; acc[rt][ct] = z;
  }
  for (int s = 0; s < 3; ++s) {
    frag_ab a0 = *(const frag_ab*)&A[(wv*32 + lrow) * AS1 + s*32 + lk*8];
    frag_ab a1 = *(const frag_ab*)&A[(wv*32 + 16 + lrow) * AS1 + s*32 + lk*8];
    for (int ct = 0; ct < 4; ++ct) {
      acc[0][ct] = __builtin_amdgcn_mfma_f32_16x16x32_bf16(a0, bf[s*4+ct], acc[0][ct], 0, 0, 0);
      acc[1][ct] = __builtin_amdgcn_mfma_f32_16x16x32_bf16(a1, bf[s*4+ct], acc[1][ct], 0, 0, 0);
    }
  }
  float bv[4];
  for (int ct = 0; ct < 4; ++ct) bv[ct] = bias[ct*16 + lrow];
  for (int rt = 0; rt < 2; ++rt)
    for (int ct = 0; ct < 4; ++ct)
      for (int r = 0; r < 4; ++r) {
        int row = wv*32 + rt*16 + lk*4 + r;
        int rg = nb + row;
        if (rg < N) hbf[(size_t)rg * 64 + ct*16 + lrow] = f2bf(acc[rt][ct][r] + bv[ct]);
      }
}

// ---------------------------------------------------------------------------
// hist: counting-sort histogram + rank, and attr fp32->bf16 (edge order).
// ---------------------------------------------------------------------------
__global__ __launch_bounds__(256) void hist_kernel(
    const int* __restrict__ dst, const float* __restrict__ attr,
    int* __restrict__ counts, int* __restrict__ rank,
    uint4* __restrict__ abf, int E)
{
  int i = blockIdx.x * 256 + threadIdx.x;
  if (i < E) {
    rank[i] = atomicAdd(&counts[dst[i]], 1);
    const float4* a4 = (const float4*)(attr + (size_t)i * 16);
    float4 v0 = a4[0], v1 = a4[1], v2 = a4[2], v3 = a4[3];
    __align__(16) short tmp[16];
    tmp[0]=f2bf(v0.x); tmp[1]=f2bf(v0.y); tmp[2]=f2bf(v0.z); tmp[3]=f2bf(v0.w);
    tmp[4]=f2bf(v1.x); tmp[5]=f2bf(v1.y); tmp[6]=f2bf(v1.z); tmp[7]=f2bf(v1.w);
    tmp[8]=f2bf(v2.x); tmp[9]=f2bf(v2.y); tmp[10]=f2bf(v2.z); tmp[11]=f2bf(v2.w);
    tmp[12]=f2bf(v3.x); tmp[13]=f2bf(v3.y); tmp[14]=f2bf(v3.z); tmp[15]=f2bf(v3.w);
    uint4* rp = abf + (size_t)i * 2;
    rp[0] = *(uint4*)&tmp[0];
    rp[1] = *(uint4*)&tmp[8];
  }
}

#define SCAN_TILE 2048
__global__ __launch_bounds__(256) void scan_k1(
    const int* __restrict__ counts, int* __restrict__ offsets,
    int* __restrict__ bsum, int n)
{
  __shared__ int ts[256];
  int t = threadIdx.x;
  int base = blockIdx.x * SCAN_TILE + t * 8;
  int v[8]; int s = 0;
  for (int j = 0; j < 8; ++j) { v[j] = (base + j < n) ? counts[base + j] : 0; s += v[j]; }
  ts[t] = s; __syncthreads();
  for (int off = 1; off < 256; off <<= 1) {
    int x = (t >= off) ? ts[t - off] : 0;
    __syncthreads();
    ts[t] += x;
    __syncthreads();
  }
  if (t == 255) bsum[blockIdx.x] = ts[255];
  int run = (t > 0) ? ts[t - 1] : 0;
  for (int j = 0; j < 8; ++j) { if (base + j < n) offsets[base + j] = run; run += v[j]; }
}

__global__ __launch_bounds__(256) void scan_k3(
    int* __restrict__ offsets, const int* __restrict__ bsum, int n, int nb)
{
  __shared__ int adds;
  int t = threadIdx.x;
  if (t < 64) {
    int v = (t < nb) ? bsum[t] : 0;
    int x = v;
    for (int o = 1; o < 64; o <<= 1) { int y = __shfl_up(x, o); if (t >= o) x += y; }
    int b = blockIdx.x;
    int a = __shfl(x, b - 1);
    if (t == 0) adds = (b == 0) ? 0 : a;
  }
  __syncthreads();
  int add = adds;
  int base = blockIdx.x * SCAN_TILE + t;
  for (int j = 0; j < 8; ++j) { int i = base + j * 256; if (i < n) offsets[i] += add; }
}

// ---------------------------------------------------------------------------
// scatter: packed uint2 record {src(17)|dst[14:0]<<17, dst[16:15]|e<<2} per
// edge (8 B scattered). Tail: zero agg (sort scratch no longer overlays agg).
// ---------------------------------------------------------------------------
__global__ __launch_bounds__(256) void scatter_kernel(
    const int* __restrict__ src, const int* __restrict__ dst,
    const int* __restrict__ offsets, const int* __restrict__ rank,
    uint2* __restrict__ rec2, float* __restrict__ agg, int N, int E)
{
  int e = blockIdx.x * 256 + threadIdx.x;
  if (e < E) {
    int d = dst[e];
    int p = offsets[d] + rank[e];
    unsigned s = (unsigned)src[e];
    unsigned w0 = s | ((unsigned)(d & 0x7FFF) << 17);
    unsigned w1 = (unsigned)(d >> 15) | ((unsigned)e << 2);
    rec2[p] = make_uint2(w0, w1);
  }
  float4 z4 = make_float4(0.f, 0.f, 0.f, 0.f);
  int tot = N * 16;
  int stride = gridDim.x * 256;
  for (int z = blockIdx.x * 256 + threadIdx.x; z < tot; z += stride)
    ((float4*)agg)[z] = z4;
}

// ---------------------------------------------------------------------------
// msg v12: proven v9/R4 per-tile body (MS=68, zero conflicts, occ 6) but each
// block processes TWO 128-edge tiles with cross-tile prefetch: both rec loads
// issue first, then both gather sets, so tile B's ~900-cy gather latency sits
// in flight under tile A's MFMA+reduce. Clean test of the latency-chain
// hypothesis — no sync changes, no layout changes, numerics bit-identical.
// ---------------------------------------------------------------------------
#define MS 68

__device__ __forceinline__ void msg_decode(
    uint2 r0, uint2 r1, int g0, int g1, int E,
    int& s0, int& s1, int& d0, int& d1, int& e0, int& e1)
{
  s0 = (int)(r0.x & 0x1FFFFu);
  s1 = (int)(r1.x & 0x1FFFFu);
  d0 = (g0 < E) ? (int)((r0.x >> 17) | ((r0.y & 3u) << 15)) : -1;
  d1 = (g1 < E) ? (int)((r1.x >> 17) | ((r1.y & 3u) << 15)) : -1;
  e0 = (int)(r0.y >> 2);
  e1 = (int)(r1.y >> 2);
}

__device__ __forceinline__ void msg_gather(
    int s0, int s1, int e0, int e1, int lk,
    const short* __restrict__ hbf, const uint4* __restrict__ abf,
    frag_ab a[3][2])
{
  a[0][0] = *(const frag_ab*)&hbf[(size_t)s0 * 64 + lk*8];
  a[0][1] = *(const frag_ab*)&hbf[(size_t)s1 * 64 + lk*8];
  a[1][0] = *(const frag_ab*)&hbf[(size_t)s0 * 64 + 32 + lk*8];
  a[1][1] = *(const frag_ab*)&hbf[(size_t)s1 * 64 + 32 + lk*8];
  frag_ab z8 = {0,0,0,0,0,0,0,0};
  a[2][0] = z8; a[2][1] = z8;
  if (lk < 2) {
    a[2][0] = *(const frag_ab*)((const short*)abf + (size_t)e0 * 16 + lk*8);
    a[2][1] = *(const frag_ab*)((const short*)abf + (size_t)e1 * 16 + lk*8);
  }
}

__device__ __forceinline__ void msg_compute_reduce(
    frag_ab a[3][2], int d0, int d1,
    const short* __restrict__ wt, const float bv[4],
    short* __restrict__ M2, float* __restrict__ agg,
    int ln, int lo, int lrow, int lk)
{
  frag_cd acc[2][4];
#pragma unroll
  for (int rt = 0; rt < 2; ++rt)
#pragma unroll
    for (int ct = 0; ct < 4; ++ct) {
      frag_cd z = {0.f, 0.f, 0.f, 0.f}; acc[rt][ct] = z;
    }
#pragma unroll
  for (int s = 0; s < 3; ++s)
#pragma unroll
    for (int ct = 0; ct < 4; ++ct) {
      frag_ab bb = *(const frag_ab*)&wt[((size_t)(s * 4 + ct) * 64 + ln) * 8];
      acc[0][ct] = __builtin_amdgcn_mfma_f32_16x16x32_bf16(a[s][0], bb, acc[0][ct], 0, 0, 0);
      acc[1][ct] = __builtin_amdgcn_mfma_f32_16x16x32_bf16(a[s][1], bb, acc[1][ct], 0, 0, 0);
    }

  // WAR fence vs previous tile's M2 reads (wave-local, ~free: data dep done)
  __asm__ __volatile__("s_waitcnt lgkmcnt(0)" ::: "memory");
#pragma unroll
  for (int rt = 0; rt < 2; ++rt)
#pragma unroll
    for (int ct = 0; ct < 4; ++ct)
#pragma unroll
      for (int r = 0; r < 4; ++r) {
        int row = lo + rt*16 + lk*4 + r;
        float m = acc[rt][ct][r] + bv[ct];
        m = m > 0.f ? m : 0.1f * m;              // LeakyReLU(0.1)
        M2[row * MS + ct*16 + lrow] = f2bf(m);
      }
  __asm__ __volatile__("s_waitcnt lgkmcnt(0)" ::: "memory");  // wave-local

  int dl = (ln < 16) ? d0 : d1;
  int dnext = __shfl_down(dl, 1);
  bool end = (ln < 32) && ((ln == 31) || (dl != dnext));
  unsigned em = (unsigned)__ballot(end);
  unsigned cm = em & ~(em & (0u - em)) & 0x7fffffffu;

  float s = 0.f;
#pragma unroll
  for (int i = 0; i < 32; ++i) {
    s += bf2f(M2[(lo + i) * MS + ln]);
    if ((em >> i) & 1u) {
      int di = (i < 16) ? __shfl(d0, i) : __shfl(d1, i - 16);
      if (di >= 0) {
        float* dest = &agg[(size_t)di * 64 + ln];
        if ((cm >> i) & 1u) *dest = s;
        else unsafeAtomicAdd(dest, s);
      }
      s = 0.f;
    }
  }
}

__global__ __launch_bounds__(256, 6) void msg_kernel(
    const short* __restrict__ hbf, const uint2* __restrict__ rec2,
    const uint4* __restrict__ abf,
    const short* __restrict__ wt, const float* __restrict__ bias,
    float* __restrict__ agg, int E)
{
  __shared__ short M2[128 * MS];                 // 17408 B
  int t = threadIdx.x;
  // bijective XCD-aware remap (nwg % 8 != 0 safe)
  int nwg = gridDim.x, b0 = blockIdx.x;
  int q = nwg >> 3, r = nwg & 7;
  int xcd = b0 & 7, bi = b0 >> 3;
  int b = (xcd < r ? xcd * (q + 1) : r * (q + 1) + (xcd - r) * q) + bi;
  int ln = t & 63;
  int wv = t >> 6;
  int lrow = ln & 15, lk = ln >> 4;
  int lo = wv * 32;
  int base = b * 256;                            // two 128-edge tiles

  // --- both rec loads issue first (independent) ---
  int gA0 = base + lo + lrow,       gA1 = gA0 + 16;
  int gB0 = base + 128 + lo + lrow, gB1 = gB0 + 16;
  int pA0 = gA0 > E - 1 ? E - 1 : gA0;
  int pA1 = gA1 > E - 1 ? E - 1 : gA1;
  int pB0 = gB0 > E - 1 ? E - 1 : gB0;
  int pB1 = gB1 > E - 1 ? E - 1 : gB1;
  uint2 rA0 = rec2[pA0], rA1 = rec2[pA1];
  uint2 rB0 = rec2[pB0], rB1 = rec2[pB1];

  int sA0, sA1, dA0, dA1, eA0, eA1;
  int sB0, sB1, dB0, dB1, eB0, eB1;
  msg_decode(rA0, rA1, gA0, gA1, E, sA0, sA1, dA0, dA1, eA0, eA1);
  msg_decode(rB0, rB1, gB0, gB1, E, sB0, sB1, dB0, dB1, eB0, eB1);

  // --- both gather sets issue before either compute consumes ---
  frag_ab aA[3][2], aB[3][2];
  msg_gather(sA0, sA1, eA0, eA1, lk, hbf, abf, aA);
  msg_gather(sB0, sB1, eB0, eB1, lk, hbf, abf, aB);

  float bv[4];
#pragma unroll
  for (int ct = 0; ct < 4; ++ct) bv[ct] = bias[ct*16 + lrow];

  // tile A compute+reduce (tile B gathers in flight underneath)
  msg_compute_reduce(aA, dA0, dA1, wt, bv, M2, agg, ln, lo, lrow, lk);
  // tile B compute+reduce
  msg_compute_reduce(aB, dB0, dB1, wt, bv, M2, agg, ln, lo, lrow, lk);
}

// ---------------------------------------------------------------------------
// upd: unchanged R4 body (64 rows/block, fused agg re-zeroing).
// ---------------------------------------------------------------------------
__global__ __launch_bounds__(256, 4) void upd_kernel(
    const short* __restrict__ hbf, float* __restrict__ agg,
    const short* __restrict__ wt, const float* __restrict__ bias,
    float* __restrict__ hout, short* __restrict__ hbfo, int N, int last)
{
  int t = threadIdx.x;
  int nb = blockIdx.x * 64;
  int ln = t & 63;
  int wv = t >> 6;
  int lrow = ln & 15, lk = ln >> 4;
  int r0 = nb + wv*16 + lrow;

  frag_ab z8 = {0,0,0,0,0,0,0,0};
  frag_ab a[4];
  a[0] = (r0 < N) ? *(const frag_ab*)&hbf[(size_t)r0 * 64 + lk*8]      : z8;
  a[1] = (r0 < N) ? *(const frag_ab*)&hbf[(size_t)r0 * 64 + 32 + lk*8] : z8;
  for (int si = 0; si < 2; ++si) {
    int cb = si * 32 + lk * 8;
    frag_ab af = z8;
    if (r0 < N) {
      float* ap = &agg[(size_t)r0 * 64 + cb];
      float4 v0 = *(const float4*)ap;
      float4 v1 = *(const float4*)(ap + 4);
      af[0]=f2bf(v0.x); af[1]=f2bf(v0.y); af[2]=f2bf(v0.z); af[3]=f2bf(v0.w);
      af[4]=f2bf(v1.x); af[5]=f2bf(v1.y); af[6]=f2bf(v1.z); af[7]=f2bf(v1.w);
      if (!last) {
        float4 z = make_float4(0.f, 0.f, 0.f, 0.f);
        *(float4*)ap = z; *(float4*)(ap + 4) = z;
      }
    }
    a[2 + si] = af;
  }

  frag_cd acc[4];
  for (int ct = 0; ct < 4; ++ct) {
    frag_cd z = {0.f, 0.f, 0.f, 0.f}; acc[ct] = z;
  }
  for (int s = 0; s < 4; ++s)
    for (int ct = 0; ct < 4; ++ct) {
      frag_ab b = *(const frag_ab*)&wt[((size_t)(s * 4 + ct) * 64 + ln) * 8];
      acc[ct] = __builtin_amdgcn_mfma_f32_16x16x32_bf16(a[s], b, acc[ct], 0, 0, 0);
    }
  float bv[4];
  for (int ct = 0; ct < 4; ++ct) bv[ct] = bias[ct*16 + lrow];
  for (int ct = 0; ct < 4; ++ct)
    for (int r = 0; r < 4; ++r) {
      int rg = nb + wv*16 + lk*4 + r;
      if (rg < N) {
        float v = acc[ct][r] + bv[ct];
        if (last) hout[(size_t)rg * 64 + ct*16 + lrow] = v;
        hbfo[(size_t)rg * 64 + ct*16 + lrow] = f2bf(v);
      }
    }
}

extern "C" void kernel_launch(void* const* d_in, const int* in_sizes, int n_in,
                              void* d_out, int out_size, void* d_ws, size_t ws_size,
                              hipStream_t stream) {
  const float* x    = (const float*)d_in[0];
  const int*   ei   = (const int*)d_in[1];
  const float* attr = (const float*)d_in[2];
  const float* pw   = (const float*)d_in[3];
  const float* pb   = (const float*)d_in[4];
  const float* u2w  = (const float*)d_in[5];
  const float* u2b  = (const float*)d_in[6];
  const float* u1w  = (const float*)d_in[7];
  const float* u1b  = (const float*)d_in[8];

  const int N = in_sizes[0] / 75;
  const int E = in_sizes[1] / 2;
  const int* src = ei;
  const int* dst = ei + E;

  float* hout = (float*)d_out;
  char*  ws   = (char*)d_ws;
  size_t nh   = (size_t)N * 64;
  size_t off  = 0;
  short* hbf   = (short*)(ws + off); off += nh * 2;              //  12.8 MB
  float* agg   = (float*)(ws + off); off += nh * 4;              //  25.6 MB
  uint2* rec2  = (uint2*)(ws + off); off += (size_t)E * 8;       //  12.8 MB
  uint4* abf_e = (uint4*)(ws + off); off += (size_t)E * 32;      //  51.2 MB
  int*   counts  = (int*)(ws + off); off += (size_t)N * 4;
  int*   offsets = (int*)(ws + off); off += (size_t)N * 4;
  int*   bsum    = (int*)(ws + off); off += 64 * 4;
  int*   rank    = (int*)(ws + off); off += (size_t)E * 4;
  short* projt = (short*)(ws + off); off += 3 * 4 * 64 * 8 * 2;
  short* u2t   = (short*)(ws + off); off += (size_t)3 * 3 * 4 * 64 * 8 * 2;
  short* u1t   = (short*)(ws + off); off += (size_t)3 * 4 * 4 * 64 * 8 * 2;

  const int NB = (N + 127) / 128;
  const int NB2 = (N + 63) / 64;
  const int EB2 = (E + 255) / 256;               // 2 tiles per block
  const int GE = (E + 255) / 256;
  const int NS = (N + SCAN_TILE - 1) / SCAN_TILE;

  // one-time preprocessing
  wconv_all<<<24, 256, 0, stream>>>(pw, u2w, u1w, projt, u2t, u1t);
  proj_kernel<<<NB, 256, 0, stream>>>(x, projt, pb, hbf, N);
  hipMemsetAsync(counts, 0, (size_t)N * 4, stream);
  hist_kernel<<<GE, 256, 0, stream>>>(dst, attr, counts, rank, abf_e, E);
  scan_k1<<<NS, 256, 0, stream>>>(counts, offsets, bsum, N);
  scan_k3<<<NS, 256, 0, stream>>>(offsets, bsum, N, NS);
  scatter_kernel<<<GE, 256, 0, stream>>>(src, dst, offsets, rank, rec2, agg, N, E);

  for (int l = 0; l < 3; ++l) {
    msg_kernel<<<EB2, 256, 0, stream>>>(hbf, rec2, abf_e,
                                        u2t + (size_t)l * 6144, u2b + l * 64,
                                        agg, E);
    upd_kernel<<<NB2, 256, 0, stream>>>(hbf, agg,
                                        u1t + (size_t)l * 8192, u1b + l * 64,
                                        hout, hbf, N, l == 2);
  }
}

// Round 9
// 632.991 us; speedup vs baseline: 2.5656x; 1.1822x over previous
//
#include <hip/hip_runtime.h>

typedef __attribute__((ext_vector_type(8))) short frag_ab;   // 8 bf16 = 4 VGPRs
typedef __attribute__((ext_vector_type(4))) float frag_cd;   // 4 fp32 acc

__device__ __forceinline__ short f2bf(float f) {
  union { float f; unsigned u; } v; v.f = f;
  unsigned r = v.u + 0x7fffu + ((v.u >> 16) & 1u);   // RNE
  return (short)(r >> 16);
}
__device__ __forceinline__ float bf2f(short s) {
  union { unsigned u; float f; } v; v.u = ((unsigned)(unsigned short)s) << 16;
  return v.f;
}

// ---------------------------------------------------------------------------
// wconv: fp32 weights [nmat][Keff][64] -> MFMA B-fragment-ordered bf16.
// Blocks 24+ additionally zero the counts array (fused memset).
// ---------------------------------------------------------------------------
__device__ __forceinline__ void wconv_body(
    const float* __restrict__ W, short* __restrict__ out,
    int Keff, int S, int nmat, int tid)
{
  int per = S * 4 * 64;
  if (tid >= nmat * per) return;
  int m = tid / per, r = tid % per;
  int s = r / 256, ct = (r >> 6) & 3, ln = r & 63;
  const float* Wm = W + (size_t)m * Keff * 64;
  __align__(16) short tmp[8];
  for (int j = 0; j < 8; ++j) {
    int k = s * 32 + (ln >> 4) * 8 + j;
    int n = ct * 16 + (ln & 15);
    tmp[j] = (k < Keff) ? f2bf(Wm[k * 64 + n]) : (short)0;
  }
  *(uint4*)&out[((size_t)m * per + (size_t)(s * 4 + ct) * 64 + ln) * 8] = *(uint4*)tmp;
}

__global__ void wconv_all(const float* __restrict__ pw,
                          const float* __restrict__ u2w,
                          const float* __restrict__ u1w,
                          short* projt, short* u2t, short* u1t,
                          int* __restrict__ counts, int N)
{
  int b = blockIdx.x, t = threadIdx.x;
  if (b < 3)        wconv_body(pw,  projt, 75,  3, 1, b * 256 + t);
  else if (b < 12)  wconv_body(u2w, u2t,   80,  3, 3, (b - 3) * 256 + t);
  else if (b < 28)  wconv_body(u1w, u1t,   128, 4, 3, (b - 12) * 256 + t);
  else {
    // fused: zero counts[N] (int4 stores)
    int i = (b - 28) * 256 + t;
    int tot4 = N >> 2;
    if (i < tot4) ((int4*)counts)[i] = make_int4(0, 0, 0, 0);
    if (i == 0) for (int j = tot4 << 2; j < N; ++j) counts[j] = 0;
  }
}

// ---------------------------------------------------------------------------
// proj: hbf = bf16(x @ pw + pb).
// ---------------------------------------------------------------------------
#define AS1 104
__global__ __launch_bounds__(256, 4) void proj_kernel(
    const float* __restrict__ x, const short* __restrict__ wt,
    const float* __restrict__ bias, short* __restrict__ hbf, int N)
{
  __shared__ __align__(16) short A[128 * AS1];
  int t = threadIdx.x;
  int nb = blockIdx.x * 128;
  int ln = t & 63;
  frag_ab bf[12];
  for (int s = 0; s < 3; ++s)
    for (int ct = 0; ct < 4; ++ct)
      bf[s * 4 + ct] = *(const frag_ab*)&wt[((size_t)(s * 4 + ct) * 64 + ln) * 8];
  for (int i = 0; i < 48; ++i) {
    int q = i * 256 + t; int el = q / 96; int c = q - el * 96;
    int rg = nb + el;
    float v = (c < 75 && rg < N) ? x[rg * 75 + c] : 0.f;
    A[el * AS1 + c] = f2bf(v);
  }
  __syncthreads();
  int wv = t >> 6;
  int lrow = ln & 15, lk = ln >> 4;
  frag_cd acc[2][4];
  for (int rt = 0; rt < 2; ++rt) for (int ct = 0; ct < 4; ++ct) {
    frag_cd z = {0.f, 0.f, 0.f, 0.f}; acc[rt][ct] = z;
  }
  for (int s = 0; s < 3; ++s) {
    frag_ab a0 = *(const frag_ab*)&A[(wv*32 + lrow) * AS1 + s*32 + lk*8];
    frag_ab a1 = *(const frag_ab*)&A[(wv*32 + 16 + lrow) * AS1 + s*32 + lk*8];
    for (int ct = 0; ct < 4; ++ct) {
      acc[0][ct] = __builtin_amdgcn_mfma_f32_16x16x32_bf16(a0, bf[s*4+ct], acc[0][ct], 0, 0, 0);
      acc[1][ct] = __builtin_amdgcn_mfma_f32_16x16x32_bf16(a1, bf[s*4+ct], acc[1][ct], 0, 0, 0);
    }
  }
  float bv[4];
  for (int ct = 0; ct < 4; ++ct) bv[ct] = bias[ct*16 + lrow];
  for (int rt = 0; rt < 2; ++rt)
    for (int ct = 0; ct < 4; ++ct)
      for (int r = 0; r < 4; ++r) {
        int row = wv*32 + rt*16 + lk*4 + r;
        int rg = nb + row;
        if (rg < N) hbf[(size_t)rg * 64 + ct*16 + lrow] = f2bf(acc[rt][ct][r] + bv[ct]);
      }
}

// ---------------------------------------------------------------------------
// hist: counting-sort histogram + rank, and attr fp32->bf16 (edge order).
// ---------------------------------------------------------------------------
__global__ __launch_bounds__(256) void hist_kernel(
    const int* __restrict__ dst, const float* __restrict__ attr,
    int* __restrict__ counts, int* __restrict__ rank,
    uint4* __restrict__ abf, int E)
{
  int i = blockIdx.x * 256 + threadIdx.x;
  if (i < E) {
    rank[i] = atomicAdd(&counts[dst[i]], 1);
    const float4* a4 = (const float4*)(attr + (size_t)i * 16);
    float4 v0 = a4[0], v1 = a4[1], v2 = a4[2], v3 = a4[3];
    __align__(16) short tmp[16];
    tmp[0]=f2bf(v0.x); tmp[1]=f2bf(v0.y); tmp[2]=f2bf(v0.z); tmp[3]=f2bf(v0.w);
    tmp[4]=f2bf(v1.x); tmp[5]=f2bf(v1.y); tmp[6]=f2bf(v1.z); tmp[7]=f2bf(v1.w);
    tmp[8]=f2bf(v2.x); tmp[9]=f2bf(v2.y); tmp[10]=f2bf(v2.z); tmp[11]=f2bf(v2.w);
    tmp[12]=f2bf(v3.x); tmp[13]=f2bf(v3.y); tmp[14]=f2bf(v3.z); tmp[15]=f2bf(v3.w);
    uint4* rp = abf + (size_t)i * 2;
    rp[0] = *(uint4*)&tmp[0];
    rp[1] = *(uint4*)&tmp[8];
  }
}

#define SCAN_TILE 2048
__global__ __launch_bounds__(256) void scan_k1(
    const int* __restrict__ counts, int* __restrict__ offsets,
    int* __restrict__ bsum, int n)
{
  __shared__ int ts[256];
  int t = threadIdx.x;
  int base = blockIdx.x * SCAN_TILE + t * 8;
  int v[8]; int s = 0;
  for (int j = 0; j < 8; ++j) { v[j] = (base + j < n) ? counts[base + j] : 0; s += v[j]; }
  ts[t] = s; __syncthreads();
  for (int off = 1; off < 256; off <<= 1) {
    int x = (t >= off) ? ts[t - off] : 0;
    __syncthreads();
    ts[t] += x;
    __syncthreads();
  }
  if (t == 255) bsum[blockIdx.x] = ts[255];
  int run = (t > 0) ? ts[t - 1] : 0;
  for (int j = 0; j < 8; ++j) { if (base + j < n) offsets[base + j] = run; run += v[j]; }
}

__global__ __launch_bounds__(256) void scan_k3(
    int* __restrict__ offsets, const int* __restrict__ bsum, int n, int nb)
{
  __shared__ int adds;
  int t = threadIdx.x;
  if (t < 64) {
    int v = (t < nb) ? bsum[t] : 0;
    int x = v;
    for (int o = 1; o < 64; o <<= 1) { int y = __shfl_up(x, o); if (t >= o) x += y; }
    int b = blockIdx.x;
    int a = __shfl(x, b - 1);
    if (t == 0) adds = (b == 0) ? 0 : a;
  }
  __syncthreads();
  int add = adds;
  int base = blockIdx.x * SCAN_TILE + t;
  for (int j = 0; j < 8; ++j) { int i = base + j * 256; if (i < n) offsets[i] += add; }
}

// ---------------------------------------------------------------------------
// scatter: packed uint2 record {src(17)|dst[14:0]<<17, dst[16:15]|e<<2} per
// edge (8 B scattered). Tail: zero agg (sort scratch does NOT overlay agg).
// ---------------------------------------------------------------------------
__global__ __launch_bounds__(256) void scatter_kernel(
    const int* __restrict__ src, const int* __restrict__ dst,
    const int* __restrict__ offsets, const int* __restrict__ rank,
    uint2* __restrict__ rec2, float* __restrict__ agg, int N, int E)
{
  int e = blockIdx.x * 256 + threadIdx.x;
  if (e < E) {
    int d = dst[e];
    int p = offsets[d] + rank[e];
    unsigned s = (unsigned)src[e];
    unsigned w0 = s | ((unsigned)(d & 0x7FFF) << 17);
    unsigned w1 = (unsigned)(d >> 15) | ((unsigned)e << 2);
    rec2[p] = make_uint2(w0, w1);
  }
  float4 z4 = make_float4(0.f, 0.f, 0.f, 0.f);
  int tot = N * 16;
  int stride = gridDim.x * 256;
  for (int z = blockIdx.x * 256 + threadIdx.x; z < tot; z += stride)
    ((float4*)agg)[z] = z4;
}

// ---------------------------------------------------------------------------
// msg v10 (R4-proven, byte-identical body): wave-independent, MS=68 (zero
// LDS conflicts), occ 6 (measured equilibrium: more concurrency self-inflates
// L2-miss traffic — R5/R6/R8; less exposes gather latency). Random bf16 attr
// gather via edge id (sorted-attr A/B'd neutral). Single tile per block:
// 2-tile pipelining measured WORSE (R8: +27 us, traffic +105 MB).
// ---------------------------------------------------------------------------
#define MS 68
__global__ __launch_bounds__(256, 6) void msg_kernel(
    const short* __restrict__ hbf, const uint2* __restrict__ rec2,
    const uint4* __restrict__ abf,
    const short* __restrict__ wt, const float* __restrict__ bias,
    float* __restrict__ agg, int E)
{
  __shared__ short M2[128 * MS];                 // bf16 M, 17408 B
  int t = threadIdx.x;
  // bijective XCD-aware remap (nwg % 8 != 0 safe)
  int nwg = gridDim.x, b0 = blockIdx.x;
  int q = nwg >> 3, r = nwg & 7;
  int xcd = b0 & 7, bi = b0 >> 3;
  int b = (xcd < r ? xcd * (q + 1) : r * (q + 1) + (xcd - r) * q) + bi;
  int eb = b * 128;
  int ln = t & 63;
  int wv = t >> 6;
  int lrow = ln & 15, lk = ln >> 4;
  int lo = wv * 32;

  int g0 = eb + lo + lrow;                       // this lane's two edge rows
  int g1 = g0 + 16;
  int p0 = g0 > E - 1 ? E - 1 : g0;
  int p1 = g1 > E - 1 ? E - 1 : g1;
  uint2 r0 = rec2[p0];
  uint2 r1 = rec2[p1];
  int s0 = (int)(r0.x & 0x1FFFFu);
  int s1 = (int)(r1.x & 0x1FFFFu);
  int dd0 = (int)((r0.x >> 17) | ((r0.y & 3u) << 15));
  int dd1 = (int)((r1.x >> 17) | ((r1.y & 3u) << 15));
  int e0 = (int)(r0.y >> 2);
  int e1 = (int)(r1.y >> 2);
  int d0 = (g0 < E) ? dd0 : -1;
  int d1 = (g1 < E) ? dd1 : -1;

  frag_ab a[3][2];
  a[0][0] = *(const frag_ab*)&hbf[(size_t)s0 * 64 + lk*8];
  a[0][1] = *(const frag_ab*)&hbf[(size_t)s1 * 64 + lk*8];
  a[1][0] = *(const frag_ab*)&hbf[(size_t)s0 * 64 + 32 + lk*8];
  a[1][1] = *(const frag_ab*)&hbf[(size_t)s1 * 64 + 32 + lk*8];
  frag_ab z8 = {0,0,0,0,0,0,0,0};
  frag_ab at0 = z8, at1 = z8;
  if (lk < 2) {
    at0 = *(const frag_ab*)((const short*)abf + (size_t)e0 * 16 + lk*8);
    at1 = *(const frag_ab*)((const short*)abf + (size_t)e1 * 16 + lk*8);
  }
  a[2][0] = at0;
  a[2][1] = at1;

  frag_cd acc[2][4];
  for (int rt = 0; rt < 2; ++rt) for (int ct = 0; ct < 4; ++ct) {
    frag_cd z = {0.f, 0.f, 0.f, 0.f}; acc[rt][ct] = z;
  }
  for (int s = 0; s < 3; ++s)
    for (int ct = 0; ct < 4; ++ct) {
      frag_ab bb = *(const frag_ab*)&wt[((size_t)(s * 4 + ct) * 64 + ln) * 8];
      acc[0][ct] = __builtin_amdgcn_mfma_f32_16x16x32_bf16(a[s][0], bb, acc[0][ct], 0, 0, 0);
      acc[1][ct] = __builtin_amdgcn_mfma_f32_16x16x32_bf16(a[s][1], bb, acc[1][ct], 0, 0, 0);
    }
  float bv[4];
  for (int ct = 0; ct < 4; ++ct) bv[ct] = bias[ct*16 + lrow];

  // write this wave's 32 M rows (bf16, bias + LeakyReLU applied)
  for (int rt = 0; rt < 2; ++rt)
    for (int ct = 0; ct < 4; ++ct)
      for (int r = 0; r < 4; ++r) {
        int row = lo + rt*16 + lk*4 + r;
        float m = acc[rt][ct][r] + bv[ct];
        m = m > 0.f ? m : 0.1f * m;              // LeakyReLU(0.1)
        M2[row * MS + ct*16 + lrow] = f2bf(m);
      }
  __asm__ __volatile__("s_waitcnt lgkmcnt(0)" ::: "memory");  // wave-local

  // run structure: lanes 0..31 hold dst of rows lo+0..lo+31
  int dl = (ln < 16) ? d0 : d1;
  int dnext = __shfl_down(dl, 1);
  bool end = (ln < 32) && ((ln == 31) || (dl != dnext));
  unsigned em = (unsigned)__ballot(end);
  unsigned cm = em & ~(em & (0u - em)) & 0x7fffffffu;

  float s = 0.f;
#pragma unroll
  for (int i = 0; i < 32; ++i) {
    s += bf2f(M2[(lo + i) * MS + ln]);
    if ((em >> i) & 1u) {
      int di = (i < 16) ? __shfl(d0, i) : __shfl(d1, i - 16);
      if (di >= 0) {
        float* dest = &agg[(size_t)di * 64 + ln];
        if ((cm >> i) & 1u) *dest = s;
        else unsafeAtomicAdd(dest, s);
      }
      s = 0.f;
    }
  }
}

// ---------------------------------------------------------------------------
// upd: R4-proven body. 64 rows/block, A-frags direct from global, fused agg
// re-zeroing. In-place hbf safe (wave-private 16-row window).
// ---------------------------------------------------------------------------
__global__ __launch_bounds__(256, 4) void upd_kernel(
    const short* __restrict__ hbf, float* __restrict__ agg,
    const short* __restrict__ wt, const float* __restrict__ bias,
    float* __restrict__ hout, short* __restrict__ hbfo, int N, int last)
{
  int t = threadIdx.x;
  int nb = blockIdx.x * 64;
  int ln = t & 63;
  int wv = t >> 6;
  int lrow = ln & 15, lk = ln >> 4;
  int r0 = nb + wv*16 + lrow;

  frag_ab z8 = {0,0,0,0,0,0,0,0};
  frag_ab a[4];
  a[0] = (r0 < N) ? *(const frag_ab*)&hbf[(size_t)r0 * 64 + lk*8]      : z8;
  a[1] = (r0 < N) ? *(const frag_ab*)&hbf[(size_t)r0 * 64 + 32 + lk*8] : z8;
  for (int si = 0; si < 2; ++si) {
    int cb = si * 32 + lk * 8;
    frag_ab af = z8;
    if (r0 < N) {
      float* ap = &agg[(size_t)r0 * 64 + cb];
      float4 v0 = *(const float4*)ap;
      float4 v1 = *(const float4*)(ap + 4);
      af[0]=f2bf(v0.x); af[1]=f2bf(v0.y); af[2]=f2bf(v0.z); af[3]=f2bf(v0.w);
      af[4]=f2bf(v1.x); af[5]=f2bf(v1.y); af[6]=f2bf(v1.z); af[7]=f2bf(v1.w);
      if (!last) {
        float4 z = make_float4(0.f, 0.f, 0.f, 0.f);
        *(float4*)ap = z; *(float4*)(ap + 4) = z;
      }
    }
    a[2 + si] = af;
  }

  frag_cd acc[4];
  for (int ct = 0; ct < 4; ++ct) {
    frag_cd z = {0.f, 0.f, 0.f, 0.f}; acc[ct] = z;
  }
  for (int s = 0; s < 4; ++s)
    for (int ct = 0; ct < 4; ++ct) {
      frag_ab b = *(const frag_ab*)&wt[((size_t)(s * 4 + ct) * 64 + ln) * 8];
      acc[ct] = __builtin_amdgcn_mfma_f32_16x16x32_bf16(a[s], b, acc[ct], 0, 0, 0);
    }
  float bv[4];
  for (int ct = 0; ct < 4; ++ct) bv[ct] = bias[ct*16 + lrow];
  for (int ct = 0; ct < 4; ++ct)
    for (int r = 0; r < 4; ++r) {
      int rg = nb + wv*16 + lk*4 + r;
      if (rg < N) {
        float v = acc[ct][r] + bv[ct];
        if (last) hout[(size_t)rg * 64 + ct*16 + lrow] = v;
        hbfo[(size_t)rg * 64 + ct*16 + lrow] = f2bf(v);
      }
    }
}

extern "C" void kernel_launch(void* const* d_in, const int* in_sizes, int n_in,
                              void* d_out, int out_size, void* d_ws, size_t ws_size,
                              hipStream_t stream) {
  const float* x    = (const float*)d_in[0];
  const int*   ei   = (const int*)d_in[1];
  const float* attr = (const float*)d_in[2];
  const float* pw   = (const float*)d_in[3];
  const float* pb   = (const float*)d_in[4];
  const float* u2w  = (const float*)d_in[5];
  const float* u2b  = (const float*)d_in[6];
  const float* u1w  = (const float*)d_in[7];
  const float* u1b  = (const float*)d_in[8];

  const int N = in_sizes[0] / 75;
  const int E = in_sizes[1] / 2;
  const int* src = ei;
  const int* dst = ei + E;

  float* hout = (float*)d_out;
  char*  ws   = (char*)d_ws;
  size_t nh   = (size_t)N * 64;
  size_t off  = 0;
  short* hbf   = (short*)(ws + off); off += nh * 2;              //  12.8 MB
  float* agg   = (float*)(ws + off); off += nh * 4;              //  25.6 MB
  uint2* rec2  = (uint2*)(ws + off); off += (size_t)E * 8;       //  12.8 MB
  uint4* abf_e = (uint4*)(ws + off); off += (size_t)E * 32;      //  51.2 MB
  int*   counts  = (int*)(ws + off); off += (size_t)N * 4;       // no agg overlay
  int*   offsets = (int*)(ws + off); off += (size_t)N * 4;
  int*   bsum    = (int*)(ws + off); off += 64 * 4;
  int*   rank    = (int*)(ws + off); off += (size_t)E * 4;
  short* projt = (short*)(ws + off); off += 3 * 4 * 64 * 8 * 2;
  short* u2t   = (short*)(ws + off); off += (size_t)3 * 3 * 4 * 64 * 8 * 2;
  short* u1t   = (short*)(ws + off); off += (size_t)3 * 4 * 4 * 64 * 8 * 2;

  const int NB = (N + 127) / 128;
  const int NB2 = (N + 63) / 64;
  const int EB = (E + 127) / 128;
  const int GE = (E + 255) / 256;
  const int NS = (N + SCAN_TILE - 1) / SCAN_TILE;
  const int WCB = 28 + (N / 4 + 255) / 256;      // wconv blocks + counts-zero blocks

  // one-time preprocessing (counts-zero fused into wconv_all; agg-zero fused
  // into scatter tail — two dispatches fewer than R4)
  wconv_all<<<WCB, 256, 0, stream>>>(pw, u2w, u1w, projt, u2t, u1t, counts, N);
  proj_kernel<<<NB, 256, 0, stream>>>(x, projt, pb, hbf, N);
  hist_kernel<<<GE, 256, 0, stream>>>(dst, attr, counts, rank, abf_e, E);
  scan_k1<<<NS, 256, 0, stream>>>(counts, offsets, bsum, N);
  scan_k3<<<NS, 256, 0, stream>>>(offsets, bsum, N, NS);
  scatter_kernel<<<GE, 256, 0, stream>>>(src, dst, offsets, rank, rec2, agg, N, E);

  for (int l = 0; l < 3; ++l) {
    msg_kernel<<<EB, 256, 0, stream>>>(hbf, rec2, abf_e,
                                       u2t + (size_t)l * 6144, u2b + l * 64,
                                       agg, E);
    upd_kernel<<<NB2, 256, 0, stream>>>(hbf, agg,
                                        u1t + (size_t)l * 8192, u1b + l * 64,
                                        hout, hbf, N, l == 2);
  }
}

// Round 11
// 622.820 us; speedup vs baseline: 2.6074x; 1.0163x over previous
//
#include <hip/hip_runtime.h>

typedef __attribute__((ext_vector_type(8))) short frag_ab;   // 8 bf16 = 4 VGPRs
typedef __attribute__((ext_vector_type(4))) float frag_cd;   // 4 fp32 acc

__device__ __forceinline__ short f2bf(float f) {
  union { float f; unsigned u; } v; v.f = f;
  unsigned r = v.u + 0x7fffu + ((v.u >> 16) & 1u);   // RNE
  return (short)(r >> 16);
}
__device__ __forceinline__ float bf2f(short s) {
  union { unsigned u; float f; } v; v.u = ((unsigned)(unsigned short)s) << 16;
  return v.f;
}

// ---------------------------------------------------------------------------
// wconv: fp32 weights [nmat][Keff][64] -> MFMA B-fragment-ordered bf16.
// Blocks 28+ additionally zero the counts array (fused memset).
// ---------------------------------------------------------------------------
__device__ __forceinline__ void wconv_body(
    const float* __restrict__ W, short* __restrict__ out,
    int Keff, int S, int nmat, int tid)
{
  int per = S * 4 * 64;
  if (tid >= nmat * per) return;
  int m = tid / per, r = tid % per;
  int s = r / 256, ct = (r >> 6) & 3, ln = r & 63;
  const float* Wm = W + (size_t)m * Keff * 64;
  __align__(16) short tmp[8];
  for (int j = 0; j < 8; ++j) {
    int k = s * 32 + (ln >> 4) * 8 + j;
    int n = ct * 16 + (ln & 15);
    tmp[j] = (k < Keff) ? f2bf(Wm[k * 64 + n]) : (short)0;
  }
  *(uint4*)&out[((size_t)m * per + (size_t)(s * 4 + ct) * 64 + ln) * 8] = *(uint4*)tmp;
}

__global__ void wconv_all(const float* __restrict__ pw,
                          const float* __restrict__ u2w,
                          const float* __restrict__ u1w,
                          short* projt, short* u2t, short* u1t,
                          int* __restrict__ counts, int N)
{
  int b = blockIdx.x, t = threadIdx.x;
  if (b < 3)        wconv_body(pw,  projt, 75,  3, 1, b * 256 + t);
  else if (b < 12)  wconv_body(u2w, u2t,   80,  3, 3, (b - 3) * 256 + t);
  else if (b < 28)  wconv_body(u1w, u1t,   128, 4, 3, (b - 12) * 256 + t);
  else {
    int i = (b - 28) * 256 + t;
    int tot4 = N >> 2;
    if (i < tot4) ((int4*)counts)[i] = make_int4(0, 0, 0, 0);
    if (i == 0) for (int j = tot4 << 2; j < N; ++j) counts[j] = 0;
  }
}

// ---------------------------------------------------------------------------
// proj: hbf = bf16(x @ pw + pb).
// ---------------------------------------------------------------------------
#define AS1 104
__global__ __launch_bounds__(256, 4) void proj_kernel(
    const float* __restrict__ x, const short* __restrict__ wt,
    const float* __restrict__ bias, short* __restrict__ hbf, int N)
{
  __shared__ __align__(16) short A[128 * AS1];
  int t = threadIdx.x;
  int nb = blockIdx.x * 128;
  int ln = t & 63;
  frag_ab bf[12];
  for (int s = 0; s < 3; ++s)
    for (int ct = 0; ct < 4; ++ct)
      bf[s * 4 + ct] = *(const frag_ab*)&wt[((size_t)(s * 4 + ct) * 64 + ln) * 8];
  for (int i = 0; i < 48; ++i) {
    int q = i * 256 + t; int el = q / 96; int c = q - el * 96;
    int rg = nb + el;
    float v = (c < 75 && rg < N) ? x[rg * 75 + c] : 0.f;
    A[el * AS1 + c] = f2bf(v);
  }
  __syncthreads();
  int wv = t >> 6;
  int lrow = ln & 15, lk = ln >> 4;
  frag_cd acc[2][4];
  for (int rt = 0; rt < 2; ++rt) for (int ct = 0; ct < 4; ++ct) {
    frag_cd z = {0.f, 0.f, 0.f, 0.f}; acc[rt][ct] = z;
  }
  for (int s = 0; s < 3; ++s) {
    frag_ab a0 = *(const frag_ab*)&A[(wv*32 + lrow) * AS1 + s*32 + lk*8];
    frag_ab a1 = *(const frag_ab*)&A[(wv*32 + 16 + lrow) * AS1 + s*32 + lk*8];
    for (int ct = 0; ct < 4; ++ct) {
      acc[0][ct] = __builtin_amdgcn_mfma_f32_16x16x32_bf16(a0, bf[s*4+ct], acc[0][ct], 0, 0, 0);
      acc[1][ct] = __builtin_amdgcn_mfma_f32_16x16x32_bf16(a1, bf[s*4+ct], acc[1][ct], 0, 0, 0);
    }
  }
  float bv[4];
  for (int ct = 0; ct < 4; ++ct) bv[ct] = bias[ct*16 + lrow];
  for (int rt = 0; rt < 2; ++rt)
    for (int ct = 0; ct < 4; ++ct)
      for (int r = 0; r < 4; ++r) {
        int row = wv*32 + rt*16 + lk*4 + r;
        int rg = nb + row;
        if (rg < N) hbf[(size_t)rg * 64 + ct*16 + lrow] = f2bf(acc[rt][ct][r] + bv[ct]);
      }
}

// ---------------------------------------------------------------------------
// hist: counting-sort histogram + rank, and attr fp32->bf16 (edge order).
// ---------------------------------------------------------------------------
__global__ __launch_bounds__(256) void hist_kernel(
    const int* __restrict__ dst, const float* __restrict__ attr,
    int* __restrict__ counts, int* __restrict__ rank,
    uint4* __restrict__ abf, int E)
{
  int i = blockIdx.x * 256 + threadIdx.x;
  if (i < E) {
    rank[i] = atomicAdd(&counts[dst[i]], 1);
    const float4* a4 = (const float4*)(attr + (size_t)i * 16);
    float4 v0 = a4[0], v1 = a4[1], v2 = a4[2], v3 = a4[3];
    __align__(16) short tmp[16];
    tmp[0]=f2bf(v0.x); tmp[1]=f2bf(v0.y); tmp[2]=f2bf(v0.z); tmp[3]=f2bf(v0.w);
    tmp[4]=f2bf(v1.x); tmp[5]=f2bf(v1.y); tmp[6]=f2bf(v1.z); tmp[7]=f2bf(v1.w);
    tmp[8]=f2bf(v2.x); tmp[9]=f2bf(v2.y); tmp[10]=f2bf(v2.z); tmp[11]=f2bf(v2.w);
    tmp[12]=f2bf(v3.x); tmp[13]=f2bf(v3.y); tmp[14]=f2bf(v3.z); tmp[15]=f2bf(v3.w);
    uint4* rp = abf + (size_t)i * 2;
    rp[0] = *(uint4*)&tmp[0];
    rp[1] = *(uint4*)&tmp[8];
  }
}

#define SCAN_TILE 2048
__global__ __launch_bounds__(256) void scan_k1(
    const int* __restrict__ counts, int* __restrict__ offsets,
    int* __restrict__ bsum, int n)
{
  __shared__ int ts[256];
  int t = threadIdx.x;
  int base = blockIdx.x * SCAN_TILE + t * 8;
  int v[8]; int s = 0;
  for (int j = 0; j < 8; ++j) { v[j] = (base + j < n) ? counts[base + j] : 0; s += v[j]; }
  ts[t] = s; __syncthreads();
  for (int off = 1; off < 256; off <<= 1) {
    int x = (t >= off) ? ts[t - off] : 0;
    __syncthreads();
    ts[t] += x;
    __syncthreads();
  }
  if (t == 255) bsum[blockIdx.x] = ts[255];
  int run = (t > 0) ? ts[t - 1] : 0;
  for (int j = 0; j < 8; ++j) { if (base + j < n) offsets[base + j] = run; run += v[j]; }
}

__global__ __launch_bounds__(256) void scan_k3(
    int* __restrict__ offsets, const int* __restrict__ bsum, int n, int nb)
{
  __shared__ int adds;
  int t = threadIdx.x;
  if (t < 64) {
    int v = (t < nb) ? bsum[t] : 0;
    int x = v;
    for (int o = 1; o < 64; o <<= 1) { int y = __shfl_up(x, o); if (t >= o) x += y; }
    int b = blockIdx.x;
    int a = __shfl(x, b - 1);
    if (t == 0) adds = (b == 0) ? 0 : a;
  }
  __syncthreads();
  int add = adds;
  int base = blockIdx.x * SCAN_TILE + t;
  for (int j = 0; j < 8; ++j) { int i = base + j * 256; if (i < n) offsets[i] += add; }
}

// ---------------------------------------------------------------------------
// scatter: packed uint2 record {src(17)|dst[14:0]<<17, dst[16:15]|e<<2} per
// edge (8 B scattered). Zero-tail removed (R9: fused zero elongated this
// dispatch; the through-L2 zero lives in zero_agg below).
// ---------------------------------------------------------------------------
__global__ __launch_bounds__(256) void scatter_kernel(
    const int* __restrict__ src, const int* __restrict__ dst,
    const int* __restrict__ offsets, const int* __restrict__ rank,
    uint2* __restrict__ rec2, int E)
{
  int e = blockIdx.x * 256 + threadIdx.x;
  if (e < E) {
    int d = dst[e];
    int p = offsets[d] + rank[e];
    unsigned s = (unsigned)src[e];
    unsigned w0 = s | ((unsigned)(d & 0x7FFF) << 17);
    unsigned w1 = (unsigned)(d >> 15) | ((unsigned)e << 2);
    rec2[p] = make_uint2(w0, w1);
  }
}

// ---------------------------------------------------------------------------
// zero_agg: store-path zeroing (NOT hipMemsetAsync). Leaves all 25.6 MB of
// agg L2-resident at msg entry — R9 measured msg 114 -> 95.6 us from this
// (WRITE 149 -> 99 MB: RMWs hit L2 instead of HBM). Own dispatch so scatter
// isn't elongated.
// ---------------------------------------------------------------------------
__global__ __launch_bounds__(256) void zero_agg(float4* __restrict__ agg4, int tot4)
{
  float4 z4 = make_float4(0.f, 0.f, 0.f, 0.f);
  int stride = gridDim.x * 256;
  for (int i = blockIdx.x * 256 + threadIdx.x; i < tot4; i += stride)
    agg4[i] = z4;
}

// ---------------------------------------------------------------------------
// msg v10 (R9-proven body, 95.6 us): wave-independent, MS=68 (zero LDS
// conflicts). Occupancy W is a template param: L0/L2 run <6> (proven), L1
// runs <5> — within-run A/B probing the L2-thrash equilibrium downward
// (occ 8 measured worse via traffic self-inflation; <6 never tested).
// ---------------------------------------------------------------------------
#define MS 68
template<int W>
__global__ __launch_bounds__(256, W) void msg_kernel(
    const short* __restrict__ hbf, const uint2* __restrict__ rec2,
    const uint4* __restrict__ abf,
    const short* __restrict__ wt, const float* __restrict__ bias,
    float* __restrict__ agg, int E)
{
  __shared__ short M2[128 * MS];                 // bf16 M, 17408 B
  int t = threadIdx.x;
  // bijective XCD-aware remap (nwg % 8 != 0 safe)
  int nwg = gridDim.x, b0 = blockIdx.x;
  int q = nwg >> 3, r = nwg & 7;
  int xcd = b0 & 7, bi = b0 >> 3;
  int b = (xcd < r ? xcd * (q + 1) : r * (q + 1) + (xcd - r) * q) + bi;
  int eb = b * 128;
  int ln = t & 63;
  int wv = t >> 6;
  int lrow = ln & 15, lk = ln >> 4;
  int lo = wv * 32;

  int g0 = eb + lo + lrow;                       // this lane's two edge rows
  int g1 = g0 + 16;
  int p0 = g0 > E - 1 ? E - 1 : g0;
  int p1 = g1 > E - 1 ? E - 1 : g1;
  uint2 r0 = rec2[p0];
  uint2 r1 = rec2[p1];
  int s0 = (int)(r0.x & 0x1FFFFu);
  int s1 = (int)(r1.x & 0x1FFFFu);
  int dd0 = (int)((r0.x >> 17) | ((r0.y & 3u) << 15));
  int dd1 = (int)((r1.x >> 17) | ((r1.y & 3u) << 15));
  int e0 = (int)(r0.y >> 2);
  int e1 = (int)(r1.y >> 2);
  int d0 = (g0 < E) ? dd0 : -1;
  int d1 = (g1 < E) ? dd1 : -1;

  frag_ab a[3][2];
  a[0][0] = *(const frag_ab*)&hbf[(size_t)s0 * 64 + lk*8];
  a[0][1] = *(const frag_ab*)&hbf[(size_t)s1 * 64 + lk*8];
  a[1][0] = *(const frag_ab*)&hbf[(size_t)s0 * 64 + 32 + lk*8];
  a[1][1] = *(const frag_ab*)&hbf[(size_t)s1 * 64 + 32 + lk*8];
  frag_ab z8 = {0,0,0,0,0,0,0,0};
  frag_ab at0 = z8, at1 = z8;
  if (lk < 2) {
    at0 = *(const frag_ab*)((const short*)abf + (size_t)e0 * 16 + lk*8);
    at1 = *(const frag_ab*)((const short*)abf + (size_t)e1 * 16 + lk*8);
  }
  a[2][0] = at0;
  a[2][1] = at1;

  frag_cd acc[2][4];
  for (int rt = 0; rt < 2; ++rt) for (int ct = 0; ct < 4; ++ct) {
    frag_cd z = {0.f, 0.f, 0.f, 0.f}; acc[rt][ct] = z;
  }
  for (int s = 0; s < 3; ++s)
    for (int ct = 0; ct < 4; ++ct) {
      frag_ab bb = *(const frag_ab*)&wt[((size_t)(s * 4 + ct) * 64 + ln) * 8];
      acc[0][ct] = __builtin_amdgcn_mfma_f32_16x16x32_bf16(a[s][0], bb, acc[0][ct], 0, 0, 0);
      acc[1][ct] = __builtin_amdgcn_mfma_f32_16x16x32_bf16(a[s][1], bb, acc[1][ct], 0, 0, 0);
    }
  float bv[4];
  for (int ct = 0; ct < 4; ++ct) bv[ct] = bias[ct*16 + lrow];

  // write this wave's 32 M rows (bf16, bias + LeakyReLU applied)
  for (int rt = 0; rt < 2; ++rt)
    for (int ct = 0; ct < 4; ++ct)
      for (int r = 0; r < 4; ++r) {
        int row = lo + rt*16 + lk*4 + r;
        float m = acc[rt][ct][r] + bv[ct];
        m = m > 0.f ? m : 0.1f * m;              // LeakyReLU(0.1)
        M2[row * MS + ct*16 + lrow] = f2bf(m);
      }
  __asm__ __volatile__("s_waitcnt lgkmcnt(0)" ::: "memory");  // wave-local

  // run structure: lanes 0..31 hold dst of rows lo+0..lo+31
  int dl = (ln < 16) ? d0 : d1;
  int dnext = __shfl_down(dl, 1);
  bool end = (ln < 32) && ((ln == 31) || (dl != dnext));
  unsigned em = (unsigned)__ballot(end);
  unsigned cm = em & ~(em & (0u - em)) & 0x7fffffffu;

  float s = 0.f;
#pragma unroll
  for (int i = 0; i < 32; ++i) {
    s += bf2f(M2[(lo + i) * MS + ln]);
    if ((em >> i) & 1u) {
      int di = (i < 16) ? __shfl(d0, i) : __shfl(d1, i - 16);
      if (di >= 0) {
        float* dest = &agg[(size_t)di * 64 + ln];
        if ((cm >> i) & 1u) *dest = s;
        else unsafeAtomicAdd(dest, s);
      }
      s = 0.f;
    }
  }
}

// ---------------------------------------------------------------------------
// upd: R4-proven body. 64 rows/block, A-frags direct from global, fused agg
// re-zeroing via store path (keeps agg L2-warm for the next msg — protected
// mechanism). In-place hbf safe (wave-private 16-row window).
// ---------------------------------------------------------------------------
__global__ __launch_bounds__(256, 4) void upd_kernel(
    const short* __restrict__ hbf, float* __restrict__ agg,
    const short* __restrict__ wt, const float* __restrict__ bias,
    float* __restrict__ hout, short* __restrict__ hbfo, int N, int last)
{
  int t = threadIdx.x;
  int nb = blockIdx.x * 64;
  int ln = t & 63;
  int wv = t >> 6;
  int lrow = ln & 15, lk = ln >> 4;
  int r0 = nb + wv*16 + lrow;

  frag_ab z8 = {0,0,0,0,0,0,0,0};
  frag_ab a[4];
  a[0] = (r0 < N) ? *(const frag_ab*)&hbf[(size_t)r0 * 64 + lk*8]      : z8;
  a[1] = (r0 < N) ? *(const frag_ab*)&hbf[(size_t)r0 * 64 + 32 + lk*8] : z8;
  for (int si = 0; si < 2; ++si) {
    int cb = si * 32 + lk * 8;
    frag_ab af = z8;
    if (r0 < N) {
      float* ap = &agg[(size_t)r0 * 64 + cb];
      float4 v0 = *(const float4*)ap;
      float4 v1 = *(const float4*)(ap + 4);
      af[0]=f2bf(v0.x); af[1]=f2bf(v0.y); af[2]=f2bf(v0.z); af[3]=f2bf(v0.w);
      af[4]=f2bf(v1.x); af[5]=f2bf(v1.y); af[6]=f2bf(v1.z); af[7]=f2bf(v1.w);
      if (!last) {
        float4 z = make_float4(0.f, 0.f, 0.f, 0.f);
        *(float4*)ap = z; *(float4*)(ap + 4) = z;
      }
    }
    a[2 + si] = af;
  }

  frag_cd acc[4];
  for (int ct = 0; ct < 4; ++ct) {
    frag_cd z = {0.f, 0.f, 0.f, 0.f}; acc[ct] = z;
  }
  for (int s = 0; s < 4; ++s)
    for (int ct = 0; ct < 4; ++ct) {
      frag_ab b = *(const frag_ab*)&wt[((size_t)(s * 4 + ct) * 64 + ln) * 8];
      acc[ct] = __builtin_amdgcn_mfma_f32_16x16x32_bf16(a[s], b, acc[ct], 0, 0, 0);
    }
  float bv[4];
  for (int ct = 0; ct < 4; ++ct) bv[ct] = bias[ct*16 + lrow];
  for (int ct = 0; ct < 4; ++ct)
    for (int r = 0; r < 4; ++r) {
      int rg = nb + wv*16 + lk*4 + r;
      if (rg < N) {
        float v = acc[ct][r] + bv[ct];
        if (last) hout[(size_t)rg * 64 + ct*16 + lrow] = v;
        hbfo[(size_t)rg * 64 + ct*16 + lrow] = f2bf(v);
      }
    }
}

extern "C" void kernel_launch(void* const* d_in, const int* in_sizes, int n_in,
                              void* d_out, int out_size, void* d_ws, size_t ws_size,
                              hipStream_t stream) {
  const float* x    = (const float*)d_in[0];
  const int*   ei   = (const int*)d_in[1];
  const float* attr = (const float*)d_in[2];
  const float* pw   = (const float*)d_in[3];
  const float* pb   = (const float*)d_in[4];
  const float* u2w  = (const float*)d_in[5];
  const float* u2b  = (const float*)d_in[6];
  const float* u1w  = (const float*)d_in[7];
  const float* u1b  = (const float*)d_in[8];

  const int N = in_sizes[0] / 75;
  const int E = in_sizes[1] / 2;
  const int* src = ei;
  const int* dst = ei + E;

  float* hout = (float*)d_out;
  char*  ws   = (char*)d_ws;
  size_t nh   = (size_t)N * 64;
  size_t off  = 0;
  short* hbf   = (short*)(ws + off); off += nh * 2;              //  12.8 MB
  float* agg   = (float*)(ws + off); off += nh * 4;              //  25.6 MB
  uint2* rec2  = (uint2*)(ws + off); off += (size_t)E * 8;       //  12.8 MB
  uint4* abf_e = (uint4*)(ws + off); off += (size_t)E * 32;      //  51.2 MB
  int*   counts  = (int*)(ws + off); off += (size_t)N * 4;
  int*   offsets = (int*)(ws + off); off += (size_t)N * 4;
  int*   bsum    = (int*)(ws + off); off += 64 * 4;
  int*   rank    = (int*)(ws + off); off += (size_t)E * 4;
  short* projt = (short*)(ws + off); off += 3 * 4 * 64 * 8 * 2;
  short* u2t   = (short*)(ws + off); off += (size_t)3 * 3 * 4 * 64 * 8 * 2;
  short* u1t   = (short*)(ws + off); off += (size_t)3 * 4 * 4 * 64 * 8 * 2;

  const int NB = (N + 127) / 128;
  const int NB2 = (N + 63) / 64;
  const int EB = (E + 127) / 128;
  const int GE = (E + 255) / 256;
  const int NS = (N + SCAN_TILE - 1) / SCAN_TILE;
  const int WCB = 28 + (N / 4 + 255) / 256;

  wconv_all<<<WCB, 256, 0, stream>>>(pw, u2w, u1w, projt, u2t, u1t, counts, N);
  proj_kernel<<<NB, 256, 0, stream>>>(x, projt, pb, hbf, N);
  hist_kernel<<<GE, 256, 0, stream>>>(dst, attr, counts, rank, abf_e, E);
  scan_k1<<<NS, 256, 0, stream>>>(counts, offsets, bsum, N);
  scan_k3<<<NS, 256, 0, stream>>>(offsets, bsum, N, NS);
  scatter_kernel<<<GE, 256, 0, stream>>>(src, dst, offsets, rank, rec2, E);
  zero_agg<<<2048, 256, 0, stream>>>((float4*)agg, N * 16);

  for (int l = 0; l < 3; ++l) {
    if (l == 1)
      msg_kernel<5><<<EB, 256, 0, stream>>>(hbf, rec2, abf_e,
                                            u2t + (size_t)l * 6144, u2b + l * 64,
                                            agg, E);
    else
      msg_kernel<6><<<EB, 256, 0, stream>>>(hbf, rec2, abf_e,
                                            u2t + (size_t)l * 6144, u2b + l * 64,
                                            agg, E);
    upd_kernel<<<NB2, 256, 0, stream>>>(hbf, agg,
                                        u1t + (size_t)l * 8192, u1b + l * 64,
                                        hout, hbf, N, l == 2);
  }
}